// Round 11
// baseline (497.119 us; speedup 1.0000x reference)
//
#include <hip/hip_runtime.h>

typedef unsigned short u16;
typedef unsigned int   u32;
typedef float  f32x4  __attribute__((ext_vector_type(4)));
typedef short  bf16x8 __attribute__((ext_vector_type(8)));
typedef unsigned short u16x8 __attribute__((ext_vector_type(8)));
typedef unsigned short u16x4 __attribute__((ext_vector_type(4)));
typedef unsigned int   u32x2 __attribute__((ext_vector_type(2)));
typedef unsigned int   u32x4 __attribute__((ext_vector_type(4)));

#define DEV __device__ __forceinline__

constexpr int S  = 1024;
constexpr int BB = 8;
constexpr int NH = 1024;
constexpr int H  = 16;
// head dim = 64, BH = 128

DEV u16 f2bf(float f) {
  union { float f; unsigned u; } v{f};
  unsigned r = v.u + 0x7FFFu + ((v.u >> 16) & 1u);
  return (u16)(r >> 16);
}
DEV float sigm(float x) { return 1.0f / (1.0f + __expf(-x)); }
DEV float exp2a(float x) { float r; asm("v_exp_f32 %0, %1" : "=v"(r) : "v"(x)); return r; }

DEV void gload_lds16(const void* g, void* l) {
  __builtin_amdgcn_global_load_lds(
      (const __attribute__((address_space(1))) unsigned int*)g,
      (__attribute__((address_space(3))) unsigned int*)l, 16, 0, 0);
}

DEV f32x4 ntload4(const float* p) {
  return __builtin_nontemporal_load((const f32x4*)p);
}
DEV void ntstore4(f32x4 v, float* p) {
  __builtin_nontemporal_store(v, (f32x4*)p);
}

constexpr float SC = 0.18033688f;  // 0.125 * log2(e), folded into Wq/bq

// ---------------------------------------------------------------- prep (+gates blocks FIRST)
__global__ __launch_bounds__(256) void k_prep(
    const float* __restrict__ query, const float* __restrict__ key,
    const float* __restrict__ value, const float* __restrict__ qs_p,
    const float* __restrict__ ks_p,  const float* __restrict__ vs_p,
    const float* __restrict__ Wq,   const float* __restrict__ bq,
    const float* __restrict__ Wzf,  const float* __restrict__ bzf,
    u16* __restrict__ qx, u16* __restrict__ kout, u16* __restrict__ vout,
    float* __restrict__ vsg, float* __restrict__ bq2, u16* __restrict__ wq_bf)
{
  __shared__ float tile[64][65];
  if (blockIdx.x < 256) {  // ---- gates (longest pole: start first)
    int m = blockIdx.x * 4 + (threadIdx.x >> 6);
    int l = threadIdx.x & 63;
    const float* wz = Wzf + (size_t)m * NH;
    const float* wf = Wzf + (size_t)(m + NH) * NH;
    int base = l * 16;
    float za = 0.f, fa = 0.f;
#pragma unroll
    for (int i = 0; i < 16; i += 4) {
      f32x4 vp  = *(const f32x4*)(vs_p + base + i);
      f32x4 wzv = *(const f32x4*)(wz + base + i);
      f32x4 wfv = *(const f32x4*)(wf + base + i);
      float v0 = sigm(vp.x), v1 = sigm(vp.y), v2 = sigm(vp.z), v3 = sigm(vp.w);
      za += v0 * wzv.x + v1 * wzv.y + v2 * wzv.z + v3 * wzv.w;
      fa += v0 * wfv.x + v1 * wfv.y + v2 * wfv.z + v3 * wfv.w;
    }
#pragma unroll
    for (int off = 1; off < 64; off <<= 1) {
      za += __shfl_xor(za, off);
      fa += __shfl_xor(fa, off);
    }
    float z   = tanhf(za + bzf[m]);
    float f   = sigm(fa + bzf[m + NH]);
    float qsm = sigm(qs_p[m]);
    if (l == 0) {
      vsg[m] = f * z;
      bq2[m] = qsm * bq[m] * SC;
    }
    float qss = qsm * SC;
    const float* wqr = Wq + (size_t)m * NH;
    u16* dst = wq_bf + (size_t)m * NH + base;
#pragma unroll
    for (int i = 0; i < 16; i += 4) {
      f32x4 wv = *(const f32x4*)(wqr + base + i);
      u16x4 o;
      o[0] = f2bf(qss * wv.x); o[1] = f2bf(qss * wv.y);
      o[2] = f2bf(qss * wv.z); o[3] = f2bf(qss * wv.w);
      *(u16x4*)(dst + i) = o;
    }
    return;
  }
  int bx = blockIdx.x - 256;
  size_t idx = ((size_t)bx * 256 + threadIdx.x) * 8;
  {  // query -> bf16
    f32x4 a = ntload4(query + idx);
    f32x4 b = ntload4(query + idx + 4);
    u16x8 o;
    o[0] = f2bf(a.x); o[1] = f2bf(a.y); o[2] = f2bf(a.z); o[3] = f2bf(a.w);
    o[4] = f2bf(b.x); o[5] = f2bf(b.y); o[6] = f2bf(b.z); o[7] = f2bf(b.w);
    *(u16x8*)(qx + idx) = o;
  }
  {  // key * sigmoid(ks_p) -> [b][h][s][64]
    int n0 = (int)(idx & 1023);
    int b  = (int)((idx >> 10) & 7);
    int s  = (int)(idx >> 13);
    f32x4 a  = ntload4(key + idx);
    f32x4 c  = ntload4(key + idx + 4);
    f32x4 k0 = *(const f32x4*)(ks_p + n0);
    f32x4 k1 = *(const f32x4*)(ks_p + n0 + 4);
    int h = n0 >> 6, d0 = n0 & 63;
    u16* dst = kout + (((size_t)(b * H + h) * S + s) * 64 + d0);
    u16x8 o;
    o[0] = f2bf(a.x * sigm(k0.x)); o[1] = f2bf(a.y * sigm(k0.y));
    o[2] = f2bf(a.z * sigm(k0.z)); o[3] = f2bf(a.w * sigm(k0.w));
    o[4] = f2bf(c.x * sigm(k1.x)); o[5] = f2bf(c.y * sigm(k1.y));
    o[6] = f2bf(c.z * sigm(k1.z)); o[7] = f2bf(c.w * sigm(k1.w));
    *(u16x8*)dst = o;
  }
  if (bx < 2048) {  // value transpose (unscaled) -> [bh][kt][d][64 s']
    int bh = bx >> 4, kt = bx & 15;
    int b = bh >> 4, h = bh & 15;
    int t = threadIdx.x;
    int sp = t >> 2, c0 = (t & 3) * 16;
    const float* src = value + ((size_t)(kt * 64 + sp) * (BB * NH) + b * NH + h * 64 + c0);
#pragma unroll
    for (int i = 0; i < 16; i += 4) {
      f32x4 v = ntload4(src + i);
      tile[sp][c0 + i + 0] = v.x;
      tile[sp][c0 + i + 1] = v.y;
      tile[sp][c0 + i + 2] = v.z;
      tile[sp][c0 + i + 3] = v.w;
    }
    __syncthreads();
    int d = t >> 2, s0 = (t & 3) * 16;
    u16* dst = vout + (((size_t)bh * 16 + kt) * 64 + d) * 64 + s0;
    u16x8 o0, o1;
#pragma unroll
    for (int i = 0; i < 8; ++i) o0[i] = f2bf(tile[s0 + i][d]);
#pragma unroll
    for (int i = 0; i < 8; ++i) o1[i] = f2bf(tile[s0 + 8 + i][d]);
    *(u16x8*)dst       = o0;
    *(u16x8*)(dst + 8) = o1;
  }
}

// ---------------------------------------------------------------- fused q-proj + causal attention
// 4 waves, QBLK=64, 32KB LDS. In-register P exchange (cvt_pk + ds_bpermute).
// Zero-fill ownership SWAPPED: block (bh,t) fills stripe (15-t)'s t upper tiles,
// one 16KB tile per pass-2 slot (work proportional to slot count; tail collapses).
// grid 2048: b=bid&7 (XCD); idx=bid>>3: h=idx&15, t=15-(idx>>4) (longest first).
// LDS map (32KB):
//  prologue: A dbuf [0,16K), B dbuf [16K,32K); Qs overlays [0,8K)
//  pass1:    K bufs x4 [0,32K)   (two k-tiles per barrier slot)
//  pass2:    K2 dbuf [0,16K), V2 dbuf [16K,32K)
__global__ __launch_bounds__(256, 5) void k_attn(
    const u16* __restrict__ qx, const u16* __restrict__ wqb,
    const float* __restrict__ bq2, const u16* __restrict__ kws,
    const u16* __restrict__ vtw, const float* __restrict__ vsg,
    float* __restrict__ mix, float* __restrict__ wout)
{
  __shared__ __align__(16) char smem[32768];
  int bid = blockIdx.x;
  int b = bid & 7;
  int idx = bid >> 3;
  int h = idx & 15, t = 15 - (idx >> 4);
  int bh = b * 16 + h;
  int tid = threadIdx.x, w = tid >> 6, l = tid & 63;
  int g = l >> 4, lq = l & 15;
  int q0 = t * 64;
  int myq = q0 + 16 * w + lq;
  int jmax = t;                 // diagonal tile = t for all waves
  float* wbase = wout + (size_t)bh * S * S;
  int srow = l >> 3, sblk = l & 7;

  u16* As = (u16*)smem;             // prologue dbuf 4096 u16 each
  u16* Bs = (u16*)(smem + 16384);   // prologue dbuf 4096 u16 each
  u16* Qs = (u16*)smem;             // overlays A0 after prologue
  u16* K1 = (u16*)smem;             // pass1: 4 x 4096 u16
  u16* K2 = (u16*)smem;             // pass2: 2 x 4096 u16
  u16* V2 = (u16*)(smem + 16384);   // pass2: 2 x 4096 u16

  // ================= prologue: Qproj[64][64] = qx(b,stripe) @ wqb(h)^T + bq2
  {
    auto stageA = [&](int kt, int buf) {
#pragma unroll
      for (int ii = 0; ii < 2; ++ii) {
        int row = w * 16 + ii * 8 + srow;
        int blk = sblk ^ (row & 7);
        gload_lds16(qx + ((size_t)((q0 + row) * 8 + b) * 1024 + kt * 64 + blk * 8),
                    &As[buf * 4096 + (w * 2 + ii) * 512]);
      }
    };
    auto stageB = [&](int kt, int buf) {
#pragma unroll
      for (int ii = 0; ii < 2; ++ii) {
        int row = w * 16 + ii * 8 + srow;
        int blk = sblk ^ (row & 7);
        gload_lds16(wqb + ((size_t)(h * 64 + row) * 1024 + kt * 64 + blk * 8),
                    &Bs[buf * 4096 + (w * 2 + ii) * 512]);
      }
    };
    f32x4 acc[4];
    f32x4 zero4 = {0.f, 0.f, 0.f, 0.f};
#pragma unroll
    for (int fj = 0; fj < 4; ++fj) acc[fj] = zero4;
    stageA(0, 0); stageB(0, 0);
    for (int kt = 0; kt < 16; ++kt) {
      asm volatile("s_waitcnt vmcnt(0)" ::: "memory");
      __builtin_amdgcn_sched_barrier(0);
      __builtin_amdgcn_s_barrier();
      __builtin_amdgcn_sched_barrier(0);
      if (kt < 15) { stageA(kt + 1, (kt + 1) & 1); stageB(kt + 1, (kt + 1) & 1); }
      __builtin_amdgcn_sched_barrier(0);
      int ab = (kt & 1) * 4096, bb = (kt & 1) * 4096;
      __builtin_amdgcn_s_setprio(1);
#pragma unroll
      for (int kk = 0; kk < 2; ++kk) {
        int ar = 16 * w + lq;
        bf16x8 av = *(const bf16x8*)&As[ab + ar * 64 + ((((kk << 2) + g) ^ (ar & 7)) << 3)];
#pragma unroll
        for (int fj = 0; fj < 4; ++fj) {
          int br = fj * 16 + lq;
          bf16x8 bv = *(const bf16x8*)&Bs[bb + br * 64 + ((((kk << 2) + g) ^ (br & 7)) << 3)];
          acc[fj] = __builtin_amdgcn_mfma_f32_16x16x32_bf16(av, bv, acc[fj], 0, 0, 0);
        }
      }
      __builtin_amdgcn_s_setprio(0);
    }
    float bq4[4];
#pragma unroll
    for (int fj = 0; fj < 4; ++fj) bq4[fj] = bq2[h * 64 + fj * 16 + lq];
#pragma unroll
    for (int fj = 0; fj < 4; ++fj) {
      int d = fj * 16 + lq;
#pragma unroll
      for (int r = 0; r < 4; ++r) {
        int qrow = 16 * w + (g << 2) + r;
        Qs[qrow * 64 + (((fj * 2 + (d >> 3 & 1)) ^ (qrow & 7)) << 3) + (d & 7)] =
            f2bf(acc[fj][r] + bq4[fj]);
      }
    }
    __syncthreads();
  }
  bf16x8 qa[2];
#pragma unroll
  for (int kk = 0; kk < 2; ++kk) {
    int qr = 16 * w + lq;
    qa[kk] = *(const bf16x8*)&Qs[qr * 64 + ((((kk << 2) + g) ^ (qr & 7)) << 3)];
  }
  asm volatile("s_waitcnt lgkmcnt(0)" ::: "memory");
  __builtin_amdgcn_sched_barrier(0);
  __builtin_amdgcn_s_barrier();   // Qs region reusable after this

  auto stageK1 = [&](int j, int buf) {
#pragma unroll
    for (int ii = 0; ii < 2; ++ii) {
      int row = w * 16 + ii * 8 + srow;
      int blk = sblk ^ (row & 7);
      gload_lds16(kws + ((size_t)bh * S + j * 64 + row) * 64 + blk * 8,
                  &K1[buf * 4096 + (w * 2 + ii) * 512]);
    }
  };

  // ---- pass 1: row sums of exp2(s); TWO k-tiles per barrier slot (4 bufs).
  float lsum = 0.f;
  {
    stageK1(0, 0);
    if (jmax >= 1) stageK1(1, 1);
    auto qkTile = [&](int j) {
      int jb = (j & 3) * 4096;
      f32x4 sacc[4];
      f32x4 zero4 = {0.f, 0.f, 0.f, 0.f};
#pragma unroll
      for (int fj = 0; fj < 4; ++fj) sacc[fj] = zero4;
      __builtin_amdgcn_s_setprio(1);
#pragma unroll
      for (int kk = 0; kk < 2; ++kk)
#pragma unroll
        for (int fj = 0; fj < 4; ++fj) {
          int kr = fj * 16 + lq;
          bf16x8 kb = *(const bf16x8*)&K1[jb + kr * 64 + ((((kk << 2) + g) ^ (kr & 7)) << 3)];
          sacc[fj] = __builtin_amdgcn_mfma_f32_16x16x32_bf16(kb, qa[kk], sacc[fj], 0, 0, 0);
        }
      __builtin_amdgcn_s_setprio(0);
      if (j < jmax) {
#pragma unroll
        for (int fj = 0; fj < 4; ++fj)
#pragma unroll
          for (int r = 0; r < 4; ++r) lsum += exp2a(sacc[fj][r]);
      } else {
#pragma unroll
        for (int fj = 0; fj < 4; ++fj)
#pragma unroll
          for (int r = 0; r < 4; ++r) {
            int ki = j * 64 + fj * 16 + 4 * g + r;
            if (ki <= myq) lsum += exp2a(sacc[fj][r]);
          }
      }
    };
    int nslot = (jmax + 2) >> 1;
    for (int s = 0; s < nslot; ++s) {
      int j0 = 2 * s, j1 = 2 * s + 1;
      asm volatile("s_waitcnt vmcnt(0)" ::: "memory");
      __builtin_amdgcn_sched_barrier(0);
      __builtin_amdgcn_s_barrier();
      __builtin_amdgcn_sched_barrier(0);
      if (j0 + 2 <= jmax) stageK1(j0 + 2, (j0 + 2) & 3);
      if (j0 + 3 <= jmax) stageK1(j0 + 3, (j0 + 3) & 3);
      __builtin_amdgcn_sched_barrier(0);
      qkTile(j0);
      if (j1 <= jmax) qkTile(j1);
    }
  }
  lsum += __shfl_xor(lsum, 16);
  lsum += __shfl_xor(lsum, 32);
  float invl = 1.0f / lsum;

  __builtin_amdgcn_s_barrier();  // all waves done with pass-1 buffers

  // ---- pass 2: recompute, weights stores, distributed zero-fill, PV
  auto stageK2 = [&](int j, int buf) {
#pragma unroll
    for (int ii = 0; ii < 2; ++ii) {
      int row = w * 16 + ii * 8 + srow;
      int blk = sblk ^ (row & 7);
      gload_lds16(kws + ((size_t)bh * S + j * 64 + row) * 64 + blk * 8,
                  &K2[buf * 4096 + (w * 2 + ii) * 512]);
    }
  };
  auto stageV2 = [&](int j, int buf) {
#pragma unroll
    for (int ii = 0; ii < 2; ++ii) {
      int row = w * 16 + ii * 8 + srow;
      int blk = sblk ^ (row & 7);
      gload_lds16(vtw + (((size_t)bh * 16 + j) * 64 + row) * 64 + blk * 8,
                  &V2[buf * 4096 + (w * 2 + ii) * 512]);
    }
  };
  stageK2(0, 0); stageV2(0, 0);
  f32x4 oacc[4];
  {
    f32x4 zero4 = {0.f, 0.f, 0.f, 0.f};
#pragma unroll
    for (int db = 0; db < 4; ++db) oacc[db] = zero4;
  }
  // fill assignment: this block fills stripe s2 = 15-t, tiles j2 = 16-t+j (j < t)
  int s2 = 15 - t;
  float* fillrow = wout + (size_t)bh * S * S + (size_t)(s2 * 64 + w * 16 + (l >> 2)) * S + (l & 3) * 16;
  // bpermute byte indices for the P-exchange (loop-invariant)
  int srcA = ((32 * (g & 1) + lq) << 2);
  int srcB = srcA + 64;
  for (int j = 0; j <= jmax; ++j) {
    // queue at top (j>=1): [4 loads(j)][4 wstores(j-1)][4 fstores(j-1)] -> vmcnt(8)
    if (j == 0)      asm volatile("s_waitcnt vmcnt(0)" ::: "memory");
    else             asm volatile("s_waitcnt vmcnt(8)" ::: "memory");
    __builtin_amdgcn_sched_barrier(0);
    __builtin_amdgcn_s_barrier();
    __builtin_amdgcn_sched_barrier(0);
    if (j < jmax) { stageK2(j + 1, (j + 1) & 1); stageV2(j + 1, (j + 1) & 1); }
    __builtin_amdgcn_sched_barrier(0);
    int kbase = (j & 1) * 4096;
    f32x4 sacc[4];
    f32x4 zero4 = {0.f, 0.f, 0.f, 0.f};
#pragma unroll
    for (int fj = 0; fj < 4; ++fj) sacc[fj] = zero4;
    __builtin_amdgcn_s_setprio(1);
#pragma unroll
    for (int kk = 0; kk < 2; ++kk)
#pragma unroll
      for (int fj = 0; fj < 4; ++fj) {
        int kr = fj * 16 + lq;
        bf16x8 kb = *(const bf16x8*)&K2[kbase + kr * 64 + ((((kk << 2) + g) ^ (kr & 7)) << 3)];
        sacc[fj] = __builtin_amdgcn_mfma_f32_16x16x32_bf16(kb, qa[kk], sacc[fj], 0, 0, 0);
      }
    __builtin_amdgcn_s_setprio(0);
    bool diag = (j == jmax);
    // softmax in place
#pragma unroll
    for (int fj = 0; fj < 4; ++fj) {
#pragma unroll
      for (int r = 0; r < 4; ++r) {
        float e = exp2a(sacc[fj][r]) * invl;
        if (diag) {
          int ki = j * 64 + fj * 16 + 4 * g + r;
          if (ki > myq) e = 0.f;
        }
        sacc[fj][r] = e;
      }
    }
    // weight stores (after loads -> loads-first queue discipline)
#pragma unroll
    for (int fj = 0; fj < 4; ++fj)
      *(f32x4*)(wbase + (size_t)myq * S + j * 64 + fj * 16 + g * 4) = sacc[fj];
    // distributed zero-fill: one 16KB tile of stripe s2 per slot (j < t)
    if (j < jmax) {
      float* fp = fillrow + (16 - t + j) * 64;
      f32x4 z4 = {0.f, 0.f, 0.f, 0.f};
      ntstore4(z4, fp);
      ntstore4(z4, fp + 4);
      ntstore4(z4, fp + 8);
      ntstore4(z4, fp + 12);
    }
    // P -> bf16 pairs + in-register exchange
    u32 W0, W1, W2, W3, W4, W5, W6, W7;
    asm("v_cvt_pk_bf16_f32 %0, %1, %2" : "=v"(W0) : "v"(sacc[0][0]), "v"(sacc[0][1]));
    asm("v_cvt_pk_bf16_f32 %0, %1, %2" : "=v"(W1) : "v"(sacc[0][2]), "v"(sacc[0][3]));
    asm("v_cvt_pk_bf16_f32 %0, %1, %2" : "=v"(W2) : "v"(sacc[1][0]), "v"(sacc[1][1]));
    asm("v_cvt_pk_bf16_f32 %0, %1, %2" : "=v"(W3) : "v"(sacc[1][2]), "v"(sacc[1][3]));
    asm("v_cvt_pk_bf16_f32 %0, %1, %2" : "=v"(W4) : "v"(sacc[2][0]), "v"(sacc[2][1]));
    asm("v_cvt_pk_bf16_f32 %0, %1, %2" : "=v"(W5) : "v"(sacc[2][2]), "v"(sacc[2][3]));
    asm("v_cvt_pk_bf16_f32 %0, %1, %2" : "=v"(W6) : "v"(sacc[3][0]), "v"(sacc[3][1]));
    asm("v_cvt_pk_bf16_f32 %0, %1, %2" : "=v"(W7) : "v"(sacc[3][2]), "v"(sacc[3][3]));
    u32 a0 = __builtin_amdgcn_ds_bpermute(srcA, (int)W0);
    u32 a1 = __builtin_amdgcn_ds_bpermute(srcA, (int)W1);
    u32 a2 = __builtin_amdgcn_ds_bpermute(srcA, (int)W2);
    u32 a3 = __builtin_amdgcn_ds_bpermute(srcA, (int)W3);
    u32 a4 = __builtin_amdgcn_ds_bpermute(srcA, (int)W4);
    u32 a5 = __builtin_amdgcn_ds_bpermute(srcA, (int)W5);
    u32 a6 = __builtin_amdgcn_ds_bpermute(srcA, (int)W6);
    u32 a7 = __builtin_amdgcn_ds_bpermute(srcA, (int)W7);
    u32 b0 = __builtin_amdgcn_ds_bpermute(srcB, (int)W0);
    u32 b1 = __builtin_amdgcn_ds_bpermute(srcB, (int)W1);
    u32 b2 = __builtin_amdgcn_ds_bpermute(srcB, (int)W2);
    u32 b3 = __builtin_amdgcn_ds_bpermute(srcB, (int)W3);
    u32 b4 = __builtin_amdgcn_ds_bpermute(srcB, (int)W4);
    u32 b5 = __builtin_amdgcn_ds_bpermute(srcB, (int)W5);
    u32 b6 = __builtin_amdgcn_ds_bpermute(srcB, (int)W6);
    u32 b7 = __builtin_amdgcn_ds_bpermute(srcB, (int)W7);
    bool hi = (g >> 1) != 0;
    u32x4 paw0, paw1;
    paw0[0] = hi ? a2 : a0;  paw0[1] = hi ? a3 : a1;
    paw0[2] = hi ? b2 : b0;  paw0[3] = hi ? b3 : b1;
    paw1[0] = hi ? a6 : a4;  paw1[1] = hi ? a7 : a5;
    paw1[2] = hi ? b6 : b4;  paw1[3] = hi ? b7 : b5;
    bf16x8 pa0 = __builtin_bit_cast(bf16x8, paw0);
    bf16x8 pa1 = __builtin_bit_cast(bf16x8, paw1);
    // PV
    __builtin_amdgcn_s_setprio(1);
#pragma unroll
    for (int kk = 0; kk < 2; ++kk) {
      bf16x8 pa = kk ? pa1 : pa0;
#pragma unroll
      for (int db = 0; db < 4; ++db) {
        int d = db * 16 + lq;
        bf16x8 vb = *(const bf16x8*)&V2[(j & 1) * 4096 + d * 64 + ((((kk << 2) + g) ^ (d & 7)) << 3)];
        oacc[db] = __builtin_amdgcn_mfma_f32_16x16x32_bf16(pa, vb, oacc[db], 0, 0, 0);
      }
    }
    __builtin_amdgcn_s_setprio(0);
  }

  // mix store (S,B,NH) seq-first, x vsg (folded out of V), cached
  float vs4[4];
#pragma unroll
  for (int db = 0; db < 4; ++db) vs4[db] = vsg[h * 64 + db * 16 + lq];
#pragma unroll
  for (int db = 0; db < 4; ++db) {
#pragma unroll
    for (int r = 0; r < 4; ++r) {
      int qi = q0 + 16 * w + 4 * g + r;
      mix[(size_t)(qi * BB + b) * NH + h * 64 + db * 16 + lq] = oacc[db][r] * vs4[db];
    }
  }
}

// ---------------------------------------------------------------- launch
extern "C" void kernel_launch(void* const* d_in, const int* in_sizes, int n_in,
                              void* d_out, int out_size, void* d_ws, size_t ws_size,
                              hipStream_t stream) {
  (void)in_sizes; (void)n_in; (void)out_size; (void)ws_size;
  const float* query = (const float*)d_in[0];
  const float* key   = (const float*)d_in[1];
  const float* value = (const float*)d_in[2];
  const float* qs_p  = (const float*)d_in[3];
  const float* ks_p  = (const float*)d_in[4];
  const float* vs_p  = (const float*)d_in[5];
  const float* Wq    = (const float*)d_in[6];
  const float* bq    = (const float*)d_in[7];
  const float* Wzf   = (const float*)d_in[8];
  const float* bzf   = (const float*)d_in[9];
  // d_in[10] = attn_mask: causal, implemented directly

  char* ws = (char*)d_ws;
  float* vsg  = (float*)(ws + 0x1000);
  float* bq2  = (float*)(ws + 0x2000);
  u16* wq_bf  = (u16*)(ws + 0x4000);      // 2 MB
  u16* qx_bf  = (u16*)(ws + 0x204000);    // 16 MB flat (s,b,n)
  u16* k_ws   = (u16*)(ws + 0x1204000);   // 16 MB  [b][h][s][d]
  u16* vt_ws  = (u16*)(ws + 0x2204000);   // 16 MB  [bh][kt][d][s']

  float* mix  = (float*)d_out;
  float* wout = mix + (size_t)S * BB * NH;

  k_prep<<<4352, 256, 0, stream>>>(query, key, value, qs_p, ks_p, vs_p,
                                   Wq, bq, Wzf, bzf,
                                   qx_bf, k_ws, vt_ws, vsg, bq2, wq_bf);
  k_attn<<<2048, 256, 0, stream>>>(qx_bf, wq_bf, bq2, k_ws, vt_ws, vsg,
                                   mix, wout);
}

// Round 12
// 182.726 us; speedup vs baseline: 2.7206x; 2.7206x over previous
//
#include <hip/hip_runtime.h>

typedef unsigned short u16;
typedef unsigned int   u32;
typedef float  f32x4  __attribute__((ext_vector_type(4)));
typedef short  bf16x8 __attribute__((ext_vector_type(8)));
typedef unsigned short u16x8 __attribute__((ext_vector_type(8)));
typedef unsigned short u16x4 __attribute__((ext_vector_type(4)));
typedef unsigned int   u32x2 __attribute__((ext_vector_type(2)));
typedef unsigned int   u32x4 __attribute__((ext_vector_type(4)));

#define DEV __device__ __forceinline__

constexpr int S  = 1024;
constexpr int BB = 8;
constexpr int NH = 1024;
constexpr int H  = 16;
// head dim = 64, BH = 128

DEV u16 f2bf(float f) {
  union { float f; unsigned u; } v{f};
  unsigned r = v.u + 0x7FFFu + ((v.u >> 16) & 1u);
  return (u16)(r >> 16);
}
DEV float sigm(float x) { return 1.0f / (1.0f + __expf(-x)); }
DEV float exp2a(float x) { float r; asm("v_exp_f32 %0, %1" : "=v"(r) : "v"(x)); return r; }

DEV void gload_lds16(const void* g, void* l) {
  __builtin_amdgcn_global_load_lds(
      (const __attribute__((address_space(1))) unsigned int*)g,
      (__attribute__((address_space(3))) unsigned int*)l, 16, 0, 0);
}

DEV f32x4 ntload4(const float* p) {
  return __builtin_nontemporal_load((const f32x4*)p);
}
DEV void ntstore4(f32x4 v, float* p) {
  __builtin_nontemporal_store(v, (f32x4*)p);
}

constexpr float SC = 0.18033688f;  // 0.125 * log2(e), folded into Wq/bq

// ---------------------------------------------------------------- prep (gates blocks FIRST)
__global__ __launch_bounds__(256) void k_prep(
    const float* __restrict__ query, const float* __restrict__ key,
    const float* __restrict__ value, const float* __restrict__ qs_p,
    const float* __restrict__ ks_p,  const float* __restrict__ vs_p,
    const float* __restrict__ Wq,   const float* __restrict__ bq,
    const float* __restrict__ Wzf,  const float* __restrict__ bzf,
    u16* __restrict__ qx, u16* __restrict__ kout, u16* __restrict__ vout,
    float* __restrict__ vsg, float* __restrict__ bq2, u16* __restrict__ wq_bf)
{
  __shared__ float tile[64][65];
  if (blockIdx.x < 256) {  // ---- gates (longest pole: start first)
    int m = blockIdx.x * 4 + (threadIdx.x >> 6);
    int l = threadIdx.x & 63;
    const float* wz = Wzf + (size_t)m * NH;
    const float* wf = Wzf + (size_t)(m + NH) * NH;
    int base = l * 16;
    float za = 0.f, fa = 0.f;
#pragma unroll
    for (int i = 0; i < 16; i += 4) {
      f32x4 vp  = *(const f32x4*)(vs_p + base + i);
      f32x4 wzv = *(const f32x4*)(wz + base + i);
      f32x4 wfv = *(const f32x4*)(wf + base + i);
      float v0 = sigm(vp.x), v1 = sigm(vp.y), v2 = sigm(vp.z), v3 = sigm(vp.w);
      za += v0 * wzv.x + v1 * wzv.y + v2 * wzv.z + v3 * wzv.w;
      fa += v0 * wfv.x + v1 * wfv.y + v2 * wfv.z + v3 * wfv.w;
    }
#pragma unroll
    for (int off = 1; off < 64; off <<= 1) {
      za += __shfl_xor(za, off);
      fa += __shfl_xor(fa, off);
    }
    float z   = tanhf(za + bzf[m]);
    float f   = sigm(fa + bzf[m + NH]);
    float qsm = sigm(qs_p[m]);
    if (l == 0) {
      vsg[m] = f * z;
      bq2[m] = qsm * bq[m] * SC;
    }
    float qss = qsm * SC;
    const float* wqr = Wq + (size_t)m * NH;
    u16* dst = wq_bf + (size_t)m * NH + base;
#pragma unroll
    for (int i = 0; i < 16; i += 4) {
      f32x4 wv = *(const f32x4*)(wqr + base + i);
      u16x4 o;
      o[0] = f2bf(qss * wv.x); o[1] = f2bf(qss * wv.y);
      o[2] = f2bf(qss * wv.z); o[3] = f2bf(qss * wv.w);
      *(u16x4*)(dst + i) = o;
    }
    return;
  }
  int bx = blockIdx.x - 256;
  size_t idx = ((size_t)bx * 256 + threadIdx.x) * 8;
  {  // query -> bf16
    f32x4 a = ntload4(query + idx);
    f32x4 b = ntload4(query + idx + 4);
    u16x8 o;
    o[0] = f2bf(a.x); o[1] = f2bf(a.y); o[2] = f2bf(a.z); o[3] = f2bf(a.w);
    o[4] = f2bf(b.x); o[5] = f2bf(b.y); o[6] = f2bf(b.z); o[7] = f2bf(b.w);
    *(u16x8*)(qx + idx) = o;
  }
  {  // key * sigmoid(ks_p) -> [b][h][s][64]
    int n0 = (int)(idx & 1023);
    int b  = (int)((idx >> 10) & 7);
    int s  = (int)(idx >> 13);
    f32x4 a  = ntload4(key + idx);
    f32x4 c  = ntload4(key + idx + 4);
    f32x4 k0 = *(const f32x4*)(ks_p + n0);
    f32x4 k1 = *(const f32x4*)(ks_p + n0 + 4);
    int h = n0 >> 6, d0 = n0 & 63;
    u16* dst = kout + (((size_t)(b * H + h) * S + s) * 64 + d0);
    u16x8 o;
    o[0] = f2bf(a.x * sigm(k0.x)); o[1] = f2bf(a.y * sigm(k0.y));
    o[2] = f2bf(a.z * sigm(k0.z)); o[3] = f2bf(a.w * sigm(k0.w));
    o[4] = f2bf(c.x * sigm(k1.x)); o[5] = f2bf(c.y * sigm(k1.y));
    o[6] = f2bf(c.z * sigm(k1.z)); o[7] = f2bf(c.w * sigm(k1.w));
    *(u16x8*)dst = o;
  }
  if (bx < 2048) {  // value transpose (unscaled) -> [bh][kt][d][64 s']
    int bh = bx >> 4, kt = bx & 15;
    int b = bh >> 4, h = bh & 15;
    int t = threadIdx.x;
    int sp = t >> 2, c0 = (t & 3) * 16;
    const float* src = value + ((size_t)(kt * 64 + sp) * (BB * NH) + b * NH + h * 64 + c0);
#pragma unroll
    for (int i = 0; i < 16; i += 4) {
      f32x4 v = ntload4(src + i);
      tile[sp][c0 + i + 0] = v.x;
      tile[sp][c0 + i + 1] = v.y;
      tile[sp][c0 + i + 2] = v.z;
      tile[sp][c0 + i + 3] = v.w;
    }
    __syncthreads();
    int d = t >> 2, s0 = (t & 3) * 16;
    u16* dst = vout + (((size_t)bh * 16 + kt) * 64 + d) * 64 + s0;
    u16x8 o0, o1;
#pragma unroll
    for (int i = 0; i < 8; ++i) o0[i] = f2bf(tile[s0 + i][d]);
#pragma unroll
    for (int i = 0; i < 8; ++i) o1[i] = f2bf(tile[s0 + 8 + i][d]);
    *(u16x8*)dst       = o0;
    *(u16x8*)(dst + 8) = o1;
  }
}

// ---------------------------------------------------------------- fused q-proj + causal attention
// EXACT R10 structure (bench-proven 184.8us, no spill): 4 waves, QBLK=64, 32KB LDS,
// in-register P exchange (cvt_pk + ds_bpermute), end-of-kernel zero-fill.
// grid 2048: b=bid&7 (XCD); idx=bid>>3: h=idx&15, t=15-(idx>>4) (longest first).
__global__ __launch_bounds__(256, 5) void k_attn(
    const u16* __restrict__ qx, const u16* __restrict__ wqb,
    const float* __restrict__ bq2, const u16* __restrict__ kws,
    const u16* __restrict__ vtw, const float* __restrict__ vsg,
    float* __restrict__ mix, float* __restrict__ wout)
{
  __shared__ __align__(16) char smem[32768];
  int bid = blockIdx.x;
  int b = bid & 7;
  int idx = bid >> 3;
  int h = idx & 15, t = 15 - (idx >> 4);
  int bh = b * 16 + h;
  int tid = threadIdx.x, w = tid >> 6, l = tid & 63;
  int g = l >> 4, lq = l & 15;
  int q0 = t * 64;
  int myq = q0 + 16 * w + lq;
  int jmax = t;                 // diagonal tile = t for all waves
  float* wbase = wout + (size_t)bh * S * S;
  int srow = l >> 3, sblk = l & 7;

  u16* As = (u16*)smem;             // prologue dbuf 4096 u16 each
  u16* Bs = (u16*)(smem + 16384);   // prologue dbuf 4096 u16 each
  u16* Qs = (u16*)smem;             // overlays A0 after prologue
  u16* K1 = (u16*)smem;             // pass1: 4 x 4096 u16
  u16* K2 = (u16*)smem;             // pass2: 2 x 4096 u16
  u16* V2 = (u16*)(smem + 16384);   // pass2: 2 x 4096 u16

  // ================= prologue: Qproj[64][64] = qx(b,stripe) @ wqb(h)^T + bq2
  {
    auto stageA = [&](int kt, int buf) {
#pragma unroll
      for (int ii = 0; ii < 2; ++ii) {
        int row = w * 16 + ii * 8 + srow;
        int blk = sblk ^ (row & 7);
        gload_lds16(qx + ((size_t)((q0 + row) * 8 + b) * 1024 + kt * 64 + blk * 8),
                    &As[buf * 4096 + (w * 2 + ii) * 512]);
      }
    };
    auto stageB = [&](int kt, int buf) {
#pragma unroll
      for (int ii = 0; ii < 2; ++ii) {
        int row = w * 16 + ii * 8 + srow;
        int blk = sblk ^ (row & 7);
        gload_lds16(wqb + ((size_t)(h * 64 + row) * 1024 + kt * 64 + blk * 8),
                    &Bs[buf * 4096 + (w * 2 + ii) * 512]);
      }
    };
    f32x4 acc[4];
    f32x4 zero4 = {0.f, 0.f, 0.f, 0.f};
#pragma unroll
    for (int fj = 0; fj < 4; ++fj) acc[fj] = zero4;
    stageA(0, 0); stageB(0, 0);
    for (int kt = 0; kt < 16; ++kt) {
      asm volatile("s_waitcnt vmcnt(0)" ::: "memory");
      __builtin_amdgcn_sched_barrier(0);
      __builtin_amdgcn_s_barrier();
      __builtin_amdgcn_sched_barrier(0);
      if (kt < 15) { stageA(kt + 1, (kt + 1) & 1); stageB(kt + 1, (kt + 1) & 1); }
      __builtin_amdgcn_sched_barrier(0);
      int ab = (kt & 1) * 4096, bb = (kt & 1) * 4096;
      __builtin_amdgcn_s_setprio(1);
#pragma unroll
      for (int kk = 0; kk < 2; ++kk) {
        int ar = 16 * w + lq;
        bf16x8 av = *(const bf16x8*)&As[ab + ar * 64 + ((((kk << 2) + g) ^ (ar & 7)) << 3)];
#pragma unroll
        for (int fj = 0; fj < 4; ++fj) {
          int br = fj * 16 + lq;
          bf16x8 bv = *(const bf16x8*)&Bs[bb + br * 64 + ((((kk << 2) + g) ^ (br & 7)) << 3)];
          acc[fj] = __builtin_amdgcn_mfma_f32_16x16x32_bf16(av, bv, acc[fj], 0, 0, 0);
        }
      }
      __builtin_amdgcn_s_setprio(0);
    }
    float bq4[4];
#pragma unroll
    for (int fj = 0; fj < 4; ++fj) bq4[fj] = bq2[h * 64 + fj * 16 + lq];
#pragma unroll
    for (int fj = 0; fj < 4; ++fj) {
      int d = fj * 16 + lq;
#pragma unroll
      for (int r = 0; r < 4; ++r) {
        int qrow = 16 * w + (g << 2) + r;
        Qs[qrow * 64 + (((fj * 2 + (d >> 3 & 1)) ^ (qrow & 7)) << 3) + (d & 7)] =
            f2bf(acc[fj][r] + bq4[fj]);
      }
    }
    __syncthreads();
  }
  bf16x8 qa[2];
#pragma unroll
  for (int kk = 0; kk < 2; ++kk) {
    int qr = 16 * w + lq;
    qa[kk] = *(const bf16x8*)&Qs[qr * 64 + ((((kk << 2) + g) ^ (qr & 7)) << 3)];
  }
  asm volatile("s_waitcnt lgkmcnt(0)" ::: "memory");
  __builtin_amdgcn_sched_barrier(0);
  __builtin_amdgcn_s_barrier();   // Qs region reusable after this

  auto stageK1 = [&](int j, int buf) {
#pragma unroll
    for (int ii = 0; ii < 2; ++ii) {
      int row = w * 16 + ii * 8 + srow;
      int blk = sblk ^ (row & 7);
      gload_lds16(kws + ((size_t)bh * S + j * 64 + row) * 64 + blk * 8,
                  &K1[buf * 4096 + (w * 2 + ii) * 512]);
    }
  };

  // ---- pass 1: row sums of exp2(s); TWO k-tiles per barrier slot (4 bufs).
  float lsum = 0.f;
  {
    stageK1(0, 0);
    if (jmax >= 1) stageK1(1, 1);
    auto qkTile = [&](int j) {
      int jb = (j & 3) * 4096;
      f32x4 sacc[4];
      f32x4 zero4 = {0.f, 0.f, 0.f, 0.f};
#pragma unroll
      for (int fj = 0; fj < 4; ++fj) sacc[fj] = zero4;
      __builtin_amdgcn_s_setprio(1);
#pragma unroll
      for (int kk = 0; kk < 2; ++kk)
#pragma unroll
        for (int fj = 0; fj < 4; ++fj) {
          int kr = fj * 16 + lq;
          bf16x8 kb = *(const bf16x8*)&K1[jb + kr * 64 + ((((kk << 2) + g) ^ (kr & 7)) << 3)];
          sacc[fj] = __builtin_amdgcn_mfma_f32_16x16x32_bf16(kb, qa[kk], sacc[fj], 0, 0, 0);
        }
      __builtin_amdgcn_s_setprio(0);
      if (j < jmax) {
#pragma unroll
        for (int fj = 0; fj < 4; ++fj)
#pragma unroll
          for (int r = 0; r < 4; ++r) lsum += exp2a(sacc[fj][r]);
      } else {
#pragma unroll
        for (int fj = 0; fj < 4; ++fj)
#pragma unroll
          for (int r = 0; r < 4; ++r) {
            int ki = j * 64 + fj * 16 + 4 * g + r;
            if (ki <= myq) lsum += exp2a(sacc[fj][r]);
          }
      }
    };
    int nslot = (jmax + 2) >> 1;
    for (int s = 0; s < nslot; ++s) {
      int j0 = 2 * s, j1 = 2 * s + 1;
      asm volatile("s_waitcnt vmcnt(0)" ::: "memory");
      __builtin_amdgcn_sched_barrier(0);
      __builtin_amdgcn_s_barrier();
      __builtin_amdgcn_sched_barrier(0);
      if (j0 + 2 <= jmax) stageK1(j0 + 2, (j0 + 2) & 3);
      if (j0 + 3 <= jmax) stageK1(j0 + 3, (j0 + 3) & 3);
      __builtin_amdgcn_sched_barrier(0);
      qkTile(j0);
      if (j1 <= jmax) qkTile(j1);
    }
  }
  lsum += __shfl_xor(lsum, 16);
  lsum += __shfl_xor(lsum, 32);
  float invl = 1.0f / lsum;

  __builtin_amdgcn_s_barrier();  // all waves done with pass-1 buffers

  // ---- pass 2: recompute, store normalized f32 weights (cached), PV
  auto stageK2 = [&](int j, int buf) {
#pragma unroll
    for (int ii = 0; ii < 2; ++ii) {
      int row = w * 16 + ii * 8 + srow;
      int blk = sblk ^ (row & 7);
      gload_lds16(kws + ((size_t)bh * S + j * 64 + row) * 64 + blk * 8,
                  &K2[buf * 4096 + (w * 2 + ii) * 512]);
    }
  };
  auto stageV2 = [&](int j, int buf) {
#pragma unroll
    for (int ii = 0; ii < 2; ++ii) {
      int row = w * 16 + ii * 8 + srow;
      int blk = sblk ^ (row & 7);
      gload_lds16(vtw + (((size_t)bh * 16 + j) * 64 + row) * 64 + blk * 8,
                  &V2[buf * 4096 + (w * 2 + ii) * 512]);
    }
  };
  stageK2(0, 0); stageV2(0, 0);
  f32x4 oacc[4];
  {
    f32x4 zero4 = {0.f, 0.f, 0.f, 0.f};
#pragma unroll
    for (int db = 0; db < 4; ++db) oacc[db] = zero4;
  }
  // bpermute byte indices for the P-exchange (loop-invariant):
  // srcA = lane 32*(g&1)+lq, srcB = srcA+16 lanes
  int srcA = ((32 * (g & 1) + lq) << 2);
  int srcB = srcA + 64;
  for (int j = 0; j <= jmax; ++j) {
    if (j == 0) asm volatile("s_waitcnt vmcnt(0)" ::: "memory");
    else        asm volatile("s_waitcnt vmcnt(4)" ::: "memory");
    __builtin_amdgcn_sched_barrier(0);
    __builtin_amdgcn_s_barrier();
    __builtin_amdgcn_sched_barrier(0);
    if (j < jmax) { stageK2(j + 1, (j + 1) & 1); stageV2(j + 1, (j + 1) & 1); }
    __builtin_amdgcn_sched_barrier(0);
    int kbase = (j & 1) * 4096;
    f32x4 sacc[4];
    f32x4 zero4 = {0.f, 0.f, 0.f, 0.f};
#pragma unroll
    for (int fj = 0; fj < 4; ++fj) sacc[fj] = zero4;
    __builtin_amdgcn_s_setprio(1);
#pragma unroll
    for (int kk = 0; kk < 2; ++kk)
#pragma unroll
      for (int fj = 0; fj < 4; ++fj) {
        int kr = fj * 16 + lq;
        bf16x8 kb = *(const bf16x8*)&K2[kbase + kr * 64 + ((((kk << 2) + g) ^ (kr & 7)) << 3)];
        sacc[fj] = __builtin_amdgcn_mfma_f32_16x16x32_bf16(kb, qa[kk], sacc[fj], 0, 0, 0);
      }
    __builtin_amdgcn_s_setprio(0);
    bool diag = (j == jmax);
    // softmax in place
#pragma unroll
    for (int fj = 0; fj < 4; ++fj) {
#pragma unroll
      for (int r = 0; r < 4; ++r) {
        float e = exp2a(sacc[fj][r]) * invl;
        if (diag) {
          int ki = j * 64 + fj * 16 + 4 * g + r;
          if (ki > myq) e = 0.f;
        }
        sacc[fj][r] = e;
      }
    }
    // cached f32 weight stores (queue: [4 loads][these 4 stores] -> next-slot vmcnt(4) safe)
#pragma unroll
    for (int fj = 0; fj < 4; ++fj)
      *(f32x4*)(wbase + (size_t)myq * S + j * 64 + fj * 16 + g * 4) = sacc[fj];
    // P -> bf16 pairs: W[2*fj+h] = pack(p[fj][2h], p[fj][2h+1])
    u32 W0, W1, W2, W3, W4, W5, W6, W7;
    asm("v_cvt_pk_bf16_f32 %0, %1, %2" : "=v"(W0) : "v"(sacc[0][0]), "v"(sacc[0][1]));
    asm("v_cvt_pk_bf16_f32 %0, %1, %2" : "=v"(W1) : "v"(sacc[0][2]), "v"(sacc[0][3]));
    asm("v_cvt_pk_bf16_f32 %0, %1, %2" : "=v"(W2) : "v"(sacc[1][0]), "v"(sacc[1][1]));
    asm("v_cvt_pk_bf16_f32 %0, %1, %2" : "=v"(W3) : "v"(sacc[1][2]), "v"(sacc[1][3]));
    asm("v_cvt_pk_bf16_f32 %0, %1, %2" : "=v"(W4) : "v"(sacc[2][0]), "v"(sacc[2][1]));
    asm("v_cvt_pk_bf16_f32 %0, %1, %2" : "=v"(W5) : "v"(sacc[2][2]), "v"(sacc[2][3]));
    asm("v_cvt_pk_bf16_f32 %0, %1, %2" : "=v"(W6) : "v"(sacc[3][0]), "v"(sacc[3][1]));
    asm("v_cvt_pk_bf16_f32 %0, %1, %2" : "=v"(W7) : "v"(sacc[3][2]), "v"(sacc[3][3]));
    // in-register exchange: lane g pulls W[2kk+(g>>1)][h] from lanes srcA (i=0..3) and srcB (i=4..7)
    u32 a0 = __builtin_amdgcn_ds_bpermute(srcA, (int)W0);
    u32 a1 = __builtin_amdgcn_ds_bpermute(srcA, (int)W1);
    u32 a2 = __builtin_amdgcn_ds_bpermute(srcA, (int)W2);
    u32 a3 = __builtin_amdgcn_ds_bpermute(srcA, (int)W3);
    u32 a4 = __builtin_amdgcn_ds_bpermute(srcA, (int)W4);
    u32 a5 = __builtin_amdgcn_ds_bpermute(srcA, (int)W5);
    u32 a6 = __builtin_amdgcn_ds_bpermute(srcA, (int)W6);
    u32 a7 = __builtin_amdgcn_ds_bpermute(srcA, (int)W7);
    u32 b0 = __builtin_amdgcn_ds_bpermute(srcB, (int)W0);
    u32 b1 = __builtin_amdgcn_ds_bpermute(srcB, (int)W1);
    u32 b2 = __builtin_amdgcn_ds_bpermute(srcB, (int)W2);
    u32 b3 = __builtin_amdgcn_ds_bpermute(srcB, (int)W3);
    u32 b4 = __builtin_amdgcn_ds_bpermute(srcB, (int)W4);
    u32 b5 = __builtin_amdgcn_ds_bpermute(srcB, (int)W5);
    u32 b6 = __builtin_amdgcn_ds_bpermute(srcB, (int)W6);
    u32 b7 = __builtin_amdgcn_ds_bpermute(srcB, (int)W7);
    bool hi = (g >> 1) != 0;
    u32x4 paw0, paw1;
    paw0[0] = hi ? a2 : a0;  paw0[1] = hi ? a3 : a1;
    paw0[2] = hi ? b2 : b0;  paw0[3] = hi ? b3 : b1;
    paw1[0] = hi ? a6 : a4;  paw1[1] = hi ? a7 : a5;
    paw1[2] = hi ? b6 : b4;  paw1[3] = hi ? b7 : b5;
    bf16x8 pa0 = __builtin_bit_cast(bf16x8, paw0);
    bf16x8 pa1 = __builtin_bit_cast(bf16x8, paw1);
    // PV
    __builtin_amdgcn_s_setprio(1);
#pragma unroll
    for (int kk = 0; kk < 2; ++kk) {
      bf16x8 pa = kk ? pa1 : pa0;
#pragma unroll
      for (int db = 0; db < 4; ++db) {
        int d = db * 16 + lq;
        bf16x8 vb = *(const bf16x8*)&V2[(j & 1) * 4096 + d * 64 + ((((kk << 2) + g) ^ (d & 7)) << 3)];
        oacc[db] = __builtin_amdgcn_mfma_f32_16x16x32_bf16(pa, vb, oacc[db], 0, 0, 0);
      }
    }
    __builtin_amdgcn_s_setprio(0);
  }

  // mix store (S,B,NH) seq-first, x vsg (folded out of V), cached
  float vs4[4];
#pragma unroll
  for (int db = 0; db < 4; ++db) vs4[db] = vsg[h * 64 + db * 16 + lq];
#pragma unroll
  for (int db = 0; db < 4; ++db) {
#pragma unroll
    for (int r = 0; r < 4; ++r) {
      int qi = q0 + 16 * w + 4 * g + r;
      mix[(size_t)(qi * BB + b) * NH + h * 64 + db * 16 + lq] = oacc[db][r] * vs4[db];
    }
  }

  // zero-fill upper tiles of this stripe (NT: contiguous 1KB rows, no reuse)
  {
    f32x4 z4 = {0.f, 0.f, 0.f, 0.f};
    int cstart = (jmax + 1) * 64;
    for (int lr = 0; lr < 16; ++lr) {
      float* rowp = wbase + (size_t)(q0 + 16 * w + lr) * S;
      for (int c = cstart + l * 4; c < S; c += 256)
        ntstore4(z4, rowp + c);
    }
  }
}

// ---------------------------------------------------------------- launch
extern "C" void kernel_launch(void* const* d_in, const int* in_sizes, int n_in,
                              void* d_out, int out_size, void* d_ws, size_t ws_size,
                              hipStream_t stream) {
  (void)in_sizes; (void)n_in; (void)out_size; (void)ws_size;
  const float* query = (const float*)d_in[0];
  const float* key   = (const float*)d_in[1];
  const float* value = (const float*)d_in[2];
  const float* qs_p  = (const float*)d_in[3];
  const float* ks_p  = (const float*)d_in[4];
  const float* vs_p  = (const float*)d_in[5];
  const float* Wq    = (const float*)d_in[6];
  const float* bq    = (const float*)d_in[7];
  const float* Wzf   = (const float*)d_in[8];
  const float* bzf   = (const float*)d_in[9];
  // d_in[10] = attn_mask: causal, implemented directly

  char* ws = (char*)d_ws;
  float* vsg  = (float*)(ws + 0x1000);
  float* bq2  = (float*)(ws + 0x2000);
  u16* wq_bf  = (u16*)(ws + 0x4000);      // 2 MB
  u16* qx_bf  = (u16*)(ws + 0x204000);    // 16 MB flat (s,b,n)
  u16* k_ws   = (u16*)(ws + 0x1204000);   // 16 MB  [b][h][s][d]
  u16* vt_ws  = (u16*)(ws + 0x2204000);   // 16 MB  [bh][kt][d][s']

  float* mix  = (float*)d_out;
  float* wout = mix + (size_t)S * BB * NH;

  k_prep<<<4352, 256, 0, stream>>>(query, key, value, qs_p, ks_p, vs_p,
                                   Wq, bq, Wzf, bzf,
                                   qx_bf, k_ws, vt_ws, vsg, bq2, wq_bf);
  k_attn<<<2048, 256, 0, stream>>>(qx_bf, wq_bf, bq2, k_ws, vt_ws, vsg,
                                   mix, wout);
}